// Round 2
// baseline (724.430 us; speedup 1.0000x reference)
//
#include <hip/hip_runtime.h>
#include <hip/hip_bf16.h>

// ConvTSP gated-GCN forward, MI355X (gfx950).
// B=4, N=200, H=128, L=3. Float inputs/outputs are f32 (per reference),
// x_edges int32. Output f32 (B,N,N,2).
//
// Workspace (~126 MiB):
//   e      (B,N,N,H) f32   residual edge state
//   e_tmp  (B,N,N,H) bf16  pre-BN edge features of current layer
//   x, Vxe, Ux, Vx, xtmp (B,N,H) f32
//   sums[512] f32 (s1E,s2E,s1N,s2N) zeroed per layer; ss[512] scale/shift
//   cnts[2] f32; WT: 4x(128x128) bf16 pre-transposed eU_w[0..2], mlp_U_w

typedef __hip_bfloat16 bf16;
typedef __attribute__((ext_vector_type(8))) short short8_t;
typedef __attribute__((ext_vector_type(4))) float f32x4;

#define B_ 4
#define N_ 200
#define H_ 128
#define BN_ (B_ * N_)
#define MT_ 13
#define MROWS_ 208

__device__ __forceinline__ unsigned short f2b(float f) {
  unsigned int i = __float_as_uint(f);
  i = (i + 0x7fffu + ((i >> 16) & 1u)) >> 16;  // RNE
  return (unsigned short)i;
}

// ---------------- init ----------------

__global__ __launch_bounds__(128) void k_init_x(
    const float* __restrict__ coord, const float* __restrict__ w_coord,
    float* __restrict__ x) {
  int bi = blockIdx.x, h = threadIdx.x;
  float c0 = coord[bi * 2 + 0], c1 = coord[bi * 2 + 1];
  x[(size_t)bi * H_ + h] = c0 * w_coord[h] + c1 * w_coord[H_ + h];
}

__global__ __launch_bounds__(256) void k_init_e(
    const int* __restrict__ xe, const float* __restrict__ ev,
    const float* __restrict__ w_eval, const float* __restrict__ emb,
    float* __restrict__ e) {
  int bi = blockIdx.x;
  for (int q4 = threadIdx.x; q4 < N_ * 32; q4 += 256) {
    int j = q4 >> 5, h0 = (q4 & 31) << 2;
    int eidx = bi * N_ + j;
    float4 v;
    if (h0 < 64) {
      float evv = ev[eidx];
      v.x = evv * w_eval[h0 + 0];
      v.y = evv * w_eval[h0 + 1];
      v.z = evv * w_eval[h0 + 2];
      v.w = evv * w_eval[h0 + 3];
    } else {
      const float* em = emb + xe[eidx] * 64 + (h0 - 64);
      v.x = em[0]; v.y = em[1]; v.z = em[2]; v.w = em[3];
    }
    *(float4*)(e + (size_t)eidx * H_ + h0) = v;
  }
}

__global__ __launch_bounds__(256) void k_cnt(const float* __restrict__ mask,
                                             float* __restrict__ cnts) {
  int t = threadIdx.x, b = t >> 6, l = t & 63;
  float s = 0.f;
  for (int n = l; n < N_; n += 64) s += mask[b * N_ + n];
#pragma unroll
  for (int d = 1; d < 64; d <<= 1) s += __shfl_xor(s, d);
  __shared__ float ms[B_];
  if (l == 0) ms[b] = s;
  __syncthreads();
  if (t == 0) {
    float cn = 0.f, ce = 0.f;
    for (int k = 0; k < B_; ++k) { cn += ms[k]; ce += ms[k] * ms[k]; }
    cnts[0] = cn; cnts[1] = ce;
  }
}

// transpose eU_w[0..2] and mlp_U_w into [out][in] bf16
__global__ __launch_bounds__(256) void k_prep_w(const float* __restrict__ eUw,
                                                const float* __restrict__ mUw,
                                                bf16* __restrict__ WT) {
  int blk = blockIdx.x;
  const float* src = (blk < 3) ? (eUw + (size_t)blk * H_ * H_) : mUw;
  bf16* dst = WT + (size_t)blk * H_ * H_;
  for (int q = threadIdx.x; q < H_ * H_; q += 256) {
    int out = q >> 7, in = q & 127;
    dst[q] = __float2bfloat16(src[in * H_ + out]);
  }
}

// ---------------- per-layer small: node linears ----------------

__global__ __launch_bounds__(128) void k_node_lin(
    const float* __restrict__ x, const float* __restrict__ eVw,
    const float* __restrict__ eVb, const float* __restrict__ nUw,
    const float* __restrict__ nUb, const float* __restrict__ nVw,
    const float* __restrict__ nVb, const float* __restrict__ mask,
    float* __restrict__ Vxe, float* __restrict__ Ux, float* __restrict__ Vx) {
  __shared__ float xr[H_];
  int bi = blockIdx.x, h = threadIdx.x;
  xr[h] = x[(size_t)bi * H_ + h];
  __syncthreads();
  float m = mask[bi];
  float a = 0.f, bvv = 0.f, c = 0.f;
#pragma unroll 4
  for (int k = 0; k < H_; ++k) {
    float xv = xr[k];
    a   = fmaf(xv, eVw[k * H_ + h], a);
    bvv = fmaf(xv, nUw[k * H_ + h], bvv);
    c   = fmaf(xv, nVw[k * H_ + h], c);
  }
  Vxe[(size_t)bi * H_ + h] = m * (a + eVb[h]);
  Ux[(size_t)bi * H_ + h]  = m * (bvv + nUb[h]);
  Vx[(size_t)bi * H_ + h]  = m * (c + nVb[h]);
}

// ---------------- LDS staging (shared by k_edge / k_head) ----------------
// sA: 208 rows x 128 bf16, byte = row*256 + (k*2 ^ ((row&7)<<4))
// sB: 128 rows (out-col) x 128 bf16 (W^T), same swizzle.
#define STAGE_AB(EPTR, WTPTR)                                              \
  {                                                                        \
    const unsigned short* wsrc = (const unsigned short*)(WTPTR);           \
    for (int q = t * 2; q < H_ * H_; q += 512) {                           \
      unsigned int v = *(const unsigned int*)(wsrc + q);                   \
      int out = q >> 7, in0 = q & 127;                                     \
      int byo = (out << 8) + (((in0 * 2)) ^ ((out & 7) << 4));             \
      *(unsigned int*)(sB + byo) = v;                                      \
    }                                                                      \
    const float* eb = (EPTR) + (size_t)bi * N_ * H_;                       \
    for (int q4 = t; q4 < MROWS_ * 32; q4 += 256) {                        \
      int row = q4 >> 5, k0 = (q4 & 31) << 2;                              \
      float4 v = make_float4(0.f, 0.f, 0.f, 0.f);                          \
      if (row < N_) v = *(const float4*)(eb + row * H_ + k0);              \
      unsigned int p0 = ((unsigned int)f2b(v.y) << 16) | f2b(v.x);         \
      unsigned int p1 = ((unsigned int)f2b(v.w) << 16) | f2b(v.z);         \
      unsigned long long pk = ((unsigned long long)p1 << 32) | p0;         \
      int byo = (row << 8) + (((k0 * 2)) ^ ((row & 7) << 4));              \
      *(unsigned long long*)(sA + byo) = pk;                               \
    }                                                                      \
  }

// ---------------- big kernel: e_tmp GEMM + gate/agg/BN-partials ----------

__global__ __launch_bounds__(256) void k_edge(
    const float* __restrict__ e, const bf16* __restrict__ WT,
    const float* __restrict__ eUb, const float* __restrict__ Vxe,
    const float* __restrict__ Vx, const float* __restrict__ Ux,
    const float* __restrict__ mask, bf16* __restrict__ etmp,
    float* __restrict__ xtmp, float* __restrict__ sums) {
  __shared__ __align__(16) char sA[MROWS_ * 256];
  __shared__ __align__(16) char sB[H_ * 256];
  const int bi = blockIdx.x;
  const int b = bi / N_;
  const int t = threadIdx.x;
  const int lane = t & 63;
  const int w = t >> 6;

  STAGE_AB(e, WT)
  __syncthreads();

  const int n0 = w << 5;
  const int colA = n0 + (lane & 15);
  const int colB = colA + 16;
  const float mask_i = mask[bi];
  const float add0 = eUb[colA] + Vxe[(size_t)bi * H_ + colA];
  const float add1 = eUb[colB] + Vxe[(size_t)bi * H_ + colB];
  const float* VxeB = Vxe + (size_t)b * N_ * H_;
  const float* VxB  = Vx  + (size_t)b * N_ * H_;

  float agg0 = 0.f, agg1 = 0.f, den0 = 0.f, den1 = 0.f;
  float s1a = 0.f, s1b = 0.f, s2a = 0.f, s2b = 0.f;
  const int kb = (lane >> 4) << 4;  // this lane's 16B k-group offset

  for (int mt = 0; mt < MT_; ++mt) {
    f32x4 acc0 = {0.f, 0.f, 0.f, 0.f}, acc1 = {0.f, 0.f, 0.f, 0.f};
    int ra = mt * 16 + (lane & 15);
#pragma unroll
    for (int kk = 0; kk < 4; ++kk) {
      int ko = kk * 64 + kb;
      short8_t av = *(const short8_t*)(sA + (ra << 8) + (ko ^ ((ra & 7) << 4)));
      short8_t b0 = *(const short8_t*)(sB + (colA << 8) + (ko ^ ((colA & 7) << 4)));
      short8_t b1 = *(const short8_t*)(sB + (colB << 8) + (ko ^ ((colB & 7) << 4)));
      acc0 = __builtin_amdgcn_mfma_f32_16x16x32_bf16(av, b0, acc0, 0, 0, 0);
      acc1 = __builtin_amdgcn_mfma_f32_16x16x32_bf16(av, b1, acc1, 0, 0, 0);
    }
#pragma unroll
    for (int r = 0; r < 4; ++r) {
      int j = mt * 16 + ((lane >> 4) << 2) + r;
      bool valid = (j < N_);
      float mj = valid ? mask[b * N_ + j] : 0.f;
      float sqm = mask_i * mj;
      float vj0 = valid ? VxeB[(size_t)j * H_ + colA] : 0.f;
      float vj1 = valid ? VxeB[(size_t)j * H_ + colB] : 0.f;
      float t0 = acc0[r] + add0 + vj0;
      float t1 = acc1[r] + add1 + vj1;
      if (valid) {
        size_t o = ((size_t)bi * N_ + j) * H_;
        etmp[o + colA] = __float2bfloat16(t0);
        etmp[o + colB] = __float2bfloat16(t1);
      }
      float g0 = sqm / (1.f + __expf(-t0));
      float g1 = sqm / (1.f + __expf(-t1));
      float vx0 = valid ? VxB[(size_t)j * H_ + colA] : 0.f;
      float vx1 = valid ? VxB[(size_t)j * H_ + colB] : 0.f;
      agg0 = fmaf(g0, vx0, agg0);
      agg1 = fmaf(g1, vx1, agg1);
      den0 += g0; den1 += g1;
      s1a = fmaf(t0, sqm, s1a);
      s1b = fmaf(t1, sqm, s1b);
      s2a = fmaf(t0 * sqm, t0, s2a);
      s2b = fmaf(t1 * sqm, t1, s2b);
    }
  }
  // reduce over row-groups (lane bits 4,5); cols are disjoint across waves
#pragma unroll
  for (int d = 16; d <= 32; d <<= 1) {
    agg0 += __shfl_xor(agg0, d); agg1 += __shfl_xor(agg1, d);
    den0 += __shfl_xor(den0, d); den1 += __shfl_xor(den1, d);
    s1a += __shfl_xor(s1a, d);   s1b += __shfl_xor(s1b, d);
    s2a += __shfl_xor(s2a, d);   s2b += __shfl_xor(s2b, d);
  }
  if ((lane >> 4) == 0) {
    atomicAdd(&sums[colA], s1a);
    atomicAdd(&sums[colB], s1b);
    atomicAdd(&sums[H_ + colA], s2a);
    atomicAdd(&sums[H_ + colB], s2b);
    float xt0 = Ux[(size_t)bi * H_ + colA] + agg0 / (1e-20f + den0);
    float xt1 = Ux[(size_t)bi * H_ + colB] + agg1 / (1e-20f + den1);
    xtmp[(size_t)bi * H_ + colA] = xt0;
    xtmp[(size_t)bi * H_ + colB] = xt1;
    atomicAdd(&sums[2 * H_ + colA], xt0 * mask_i);
    atomicAdd(&sums[3 * H_ + colA], xt0 * xt0 * mask_i);
    atomicAdd(&sums[2 * H_ + colB], xt1 * mask_i);
    atomicAdd(&sums[3 * H_ + colB], xt1 * xt1 * mask_i);
  }
}

// ---------------- BN finalize + updates ----------------

__global__ __launch_bounds__(128) void k_stats(
    const float* __restrict__ sums, const float* __restrict__ cnts,
    const float* __restrict__ gE, const float* __restrict__ bE,
    const float* __restrict__ gN, const float* __restrict__ bN,
    float* __restrict__ ss) {
  int h = threadIdx.x;
  float cntN = cnts[0], cntE = cnts[1];
  float mE = sums[h] / cntE;
  float vE = sums[H_ + h] / cntE - mE * mE;
  float scE = gE[h] * rsqrtf(vE + 1e-5f);
  ss[h] = scE;
  ss[H_ + h] = bE[h] - mE * scE;
  float mN = sums[2 * H_ + h] / cntN;
  float vN = sums[3 * H_ + h] / cntN - mN * mN;
  float scN = gN[h] * rsqrtf(vN + 1e-5f);
  ss[2 * H_ + h] = scN;
  ss[3 * H_ + h] = bN[h] - mN * scN;
}

__global__ __launch_bounds__(128) void k_xupd(const float* __restrict__ xtmp,
                                              const float* __restrict__ mask,
                                              const float* __restrict__ ss,
                                              float* __restrict__ x) {
  int bi = blockIdx.x, h = threadIdx.x;
  float mi = mask[bi];
  float tv = xtmp[(size_t)bi * H_ + h];
  float xn = (mi > 0.f) ? fmaf(tv, ss[2 * H_ + h], ss[3 * H_ + h]) : tv;
  x[(size_t)bi * H_ + h] += fmaxf(xn, 0.f);
}

__global__ __launch_bounds__(256) void k_eupd(const bf16* __restrict__ etmp,
                                              const float* __restrict__ mask,
                                              const float* __restrict__ ss,
                                              float* __restrict__ e) {
  const int bi = blockIdx.x;
  const int b = bi / N_;
  const float mi = mask[bi];
  const unsigned short* tp = (const unsigned short*)etmp;
  for (int q4 = threadIdx.x; q4 < N_ * 32; q4 += 256) {
    int j = q4 >> 5, h0 = (q4 & 31) << 2;
    float mj = mask[b * N_ + j];
    bool msk = (mi * mj) > 0.f;
    size_t base = ((size_t)bi * N_ + j) * H_ + h0;
    ushort4 tv = *(const ushort4*)(tp + base);
    float4 evv = *(const float4*)(e + base);
    float f0 = __uint_as_float((unsigned int)tv.x << 16);
    float f1 = __uint_as_float((unsigned int)tv.y << 16);
    float f2 = __uint_as_float((unsigned int)tv.z << 16);
    float f3 = __uint_as_float((unsigned int)tv.w << 16);
    float xn0 = msk ? fmaf(f0, ss[h0 + 0], ss[H_ + h0 + 0]) : f0;
    float xn1 = msk ? fmaf(f1, ss[h0 + 1], ss[H_ + h0 + 1]) : f1;
    float xn2 = msk ? fmaf(f2, ss[h0 + 2], ss[H_ + h0 + 2]) : f2;
    float xn3 = msk ? fmaf(f3, ss[h0 + 3], ss[H_ + h0 + 3]) : f3;
    evv.x += fmaxf(xn0, 0.f);
    evv.y += fmaxf(xn1, 0.f);
    evv.z += fmaxf(xn2, 0.f);
    evv.w += fmaxf(xn3, 0.f);
    *(float4*)(e + base) = evv;
  }
}

// ---------------- head: y = relu(e@U+bU)@V + bV ----------------

__global__ __launch_bounds__(256) void k_head(
    const float* __restrict__ e, const bf16* __restrict__ UT,
    const float* __restrict__ Ub, const float* __restrict__ Vw,
    const float* __restrict__ Vb, float* __restrict__ y) {
  __shared__ __align__(16) char sA[MROWS_ * 256];
  __shared__ __align__(16) char sB[H_ * 256];
  __shared__ float part[4][MROWS_][2];
  const int bi = blockIdx.x;
  const int t = threadIdx.x;
  const int lane = t & 63;
  const int w = t >> 6;

  STAGE_AB(e, UT)
  __syncthreads();

  const int n0 = w << 5;
  const int colA = n0 + (lane & 15);
  const int colB = colA + 16;
  float bu0 = Ub[colA], bu1 = Ub[colB];
  float v00 = Vw[colA * 2], v01 = Vw[colA * 2 + 1];
  float v10 = Vw[colB * 2], v11 = Vw[colB * 2 + 1];
  const int kb = (lane >> 4) << 4;

  for (int mt = 0; mt < MT_; ++mt) {
    f32x4 acc0 = {0.f, 0.f, 0.f, 0.f}, acc1 = {0.f, 0.f, 0.f, 0.f};
    int ra = mt * 16 + (lane & 15);
#pragma unroll
    for (int kk = 0; kk < 4; ++kk) {
      int ko = kk * 64 + kb;
      short8_t av = *(const short8_t*)(sA + (ra << 8) + (ko ^ ((ra & 7) << 4)));
      short8_t b0 = *(const short8_t*)(sB + (colA << 8) + (ko ^ ((colA & 7) << 4)));
      short8_t b1 = *(const short8_t*)(sB + (colB << 8) + (ko ^ ((colB & 7) << 4)));
      acc0 = __builtin_amdgcn_mfma_f32_16x16x32_bf16(av, b0, acc0, 0, 0, 0);
      acc1 = __builtin_amdgcn_mfma_f32_16x16x32_bf16(av, b1, acc1, 0, 0, 0);
    }
#pragma unroll
    for (int r = 0; r < 4; ++r) {
      float h0v = fmaxf(acc0[r] + bu0, 0.f);
      float h1v = fmaxf(acc1[r] + bu1, 0.f);
      float p0 = h0v * v00 + h1v * v10;
      float p1 = h0v * v01 + h1v * v11;
#pragma unroll
      for (int d = 1; d < 16; d <<= 1) {
        p0 += __shfl_xor(p0, d);
        p1 += __shfl_xor(p1, d);
      }
      int j = mt * 16 + ((lane >> 4) << 2) + r;
      if ((lane & 15) == 0) { part[w][j][0] = p0; part[w][j][1] = p1; }
    }
  }
  __syncthreads();
  float vb0 = Vb[0], vb1 = Vb[1];
  for (int q = t; q < N_ * 2; q += 256) {
    int j = q >> 1, c = q & 1;
    float s = part[0][j][c] + part[1][j][c] + part[2][j][c] + part[3][j][c] +
              (c ? vb1 : vb0);
    y[((size_t)bi * N_ + j) * 2 + c] = s;
  }
}

// ---------------- launch ----------------

extern "C" void kernel_launch(void* const* d_in, const int* in_sizes, int n_in,
                              void* d_out, int out_size, void* d_ws,
                              size_t ws_size, hipStream_t stream) {
  const int*   x_edges = (const int*)d_in[0];
  const float* ev      = (const float*)d_in[1];
  const float* coord   = (const float*)d_in[2];
  const float* mask    = (const float*)d_in[3];
  const float* w_coord = (const float*)d_in[4];
  const float* w_eval  = (const float*)d_in[5];
  const float* emb     = (const float*)d_in[6];
  const float* eUw = (const float*)d_in[7];
  const float* eUb = (const float*)d_in[8];
  const float* eVw = (const float*)d_in[9];
  const float* eVb = (const float*)d_in[10];
  const float* nUw = (const float*)d_in[11];
  const float* nUb = (const float*)d_in[12];
  const float* nVw = (const float*)d_in[13];
  const float* nVb = (const float*)d_in[14];
  const float* gE  = (const float*)d_in[15];
  const float* bE  = (const float*)d_in[16];
  const float* gN  = (const float*)d_in[17];
  const float* bN  = (const float*)d_in[18];
  const float* mUw = (const float*)d_in[19];
  const float* mUb = (const float*)d_in[20];
  const float* mVw = (const float*)d_in[21];
  const float* mVb = (const float*)d_in[22];

  char* ws = (char*)d_ws;
  size_t off = 0;
  auto alloc = [&](size_t bytes) {
    void* p = ws + off;
    off += (bytes + 255) & ~(size_t)255;
    return p;
  };
  float* e    = (float*)alloc((size_t)B_ * N_ * N_ * H_ * 4);  // 81.92 MB
  bf16* etmp  = (bf16*)alloc((size_t)B_ * N_ * N_ * H_ * 2);   // 40.96 MB
  float* x    = (float*)alloc((size_t)BN_ * H_ * 4);
  float* Vxe  = (float*)alloc((size_t)BN_ * H_ * 4);
  float* Ux   = (float*)alloc((size_t)BN_ * H_ * 4);
  float* Vx   = (float*)alloc((size_t)BN_ * H_ * 4);
  float* xtmp = (float*)alloc((size_t)BN_ * H_ * 4);
  float* sums = (float*)alloc(4 * H_ * 4);
  float* ss   = (float*)alloc(4 * H_ * 4);
  float* cnts = (float*)alloc(256);
  bf16* WT    = (bf16*)alloc((size_t)4 * H_ * H_ * 2);

  k_prep_w<<<4, 256, 0, stream>>>(eUw, mUw, WT);
  k_init_x<<<BN_, 128, 0, stream>>>(coord, w_coord, x);
  k_init_e<<<BN_, 256, 0, stream>>>(x_edges, ev, w_eval, emb, e);
  k_cnt<<<1, 256, 0, stream>>>(mask, cnts);

  for (int l = 0; l < 3; ++l) {
    size_t wo = (size_t)l * H_ * H_;
    size_t bo = (size_t)l * H_;
    hipMemsetAsync(sums, 0, 4 * H_ * 4, stream);
    k_node_lin<<<BN_, 128, 0, stream>>>(x, eVw + wo, eVb + bo, nUw + wo,
                                        nUb + bo, nVw + wo, nVb + bo, mask,
                                        Vxe, Ux, Vx);
    k_edge<<<BN_, 256, 0, stream>>>(e, WT + wo, eUb + bo, Vxe, Vx, Ux, mask,
                                    etmp, xtmp, sums);
    k_stats<<<1, 128, 0, stream>>>(sums, cnts, gE + bo, bE + bo, gN + bo,
                                   bN + bo, ss);
    k_xupd<<<BN_, 128, 0, stream>>>(xtmp, mask, ss, x);
    k_eupd<<<BN_, 256, 0, stream>>>(etmp, mask, ss, e);
  }
  k_head<<<BN_, 256, 0, stream>>>(e, WT + (size_t)3 * H_ * H_, mUb, mVw, mVb,
                                  (float*)d_out);
}

// Round 3
// 405.274 us; speedup vs baseline: 1.7875x; 1.7875x over previous
//
#include <hip/hip_runtime.h>
#include <hip/hip_bf16.h>

// ConvTSP gated-GCN forward, MI355X (gfx950). Round 3.
// B=4, N=200, H=128, L=3. f32 in/out, x_edges int32.
//
// Key structure vs round 2:
//  - B (weights) in 32 VGPRs/wave (loaded from L2-hot WT), no sB in LDS.
//    LDS = sA only = 53,248 B -> 3 blocks/CU (launch_bounds(256,3)).
//  - e-residual update FUSED into next kernel's staging (in-place, each
//    block owns row bi of e/etmp). k_eupd and k_init_e eliminated.
//  - k_head fuses the final update; e3 never written.

typedef __hip_bfloat16 bf16;
typedef __attribute__((ext_vector_type(8))) short short8_t;
typedef __attribute__((ext_vector_type(4))) float f32x4;

#define B_ 4
#define N_ 200
#define H_ 128
#define BN_ (B_ * N_)
#define MT_ 13
#define MROWS_ 208

__device__ __forceinline__ unsigned short f2b(float f) {
  unsigned int i = __float_as_uint(f);
  i = (i + 0x7fffu + ((i >> 16) & 1u)) >> 16;  // RNE
  return (unsigned short)i;
}
__device__ __forceinline__ float b2f16(unsigned short u) {
  return __uint_as_float((unsigned int)u << 16);
}

// ---------------- init ----------------

__global__ __launch_bounds__(128) void k_init_x(
    const float* __restrict__ coord, const float* __restrict__ w_coord,
    float* __restrict__ x) {
  int bi = blockIdx.x, h = threadIdx.x;
  float c0 = coord[bi * 2 + 0], c1 = coord[bi * 2 + 1];
  x[(size_t)bi * H_ + h] = c0 * w_coord[h] + c1 * w_coord[H_ + h];
}

__global__ __launch_bounds__(256) void k_cnt(const float* __restrict__ mask,
                                             float* __restrict__ cnts) {
  int t = threadIdx.x, b = t >> 6, l = t & 63;
  float s = 0.f;
  for (int n = l; n < N_; n += 64) s += mask[b * N_ + n];
#pragma unroll
  for (int d = 1; d < 64; d <<= 1) s += __shfl_xor(s, d);
  __shared__ float ms[B_];
  if (l == 0) ms[b] = s;
  __syncthreads();
  if (t == 0) {
    float cn = 0.f, ce = 0.f;
    for (int k = 0; k < B_; ++k) { cn += ms[k]; ce += ms[k] * ms[k]; }
    cnts[0] = cn; cnts[1] = ce;
  }
}

// transpose eU_w[0..2] and mlp_U_w into [out][in] bf16
__global__ __launch_bounds__(256) void k_prep_w(const float* __restrict__ eUw,
                                                const float* __restrict__ mUw,
                                                bf16* __restrict__ WT) {
  int blk = blockIdx.x;
  const float* src = (blk < 3) ? (eUw + (size_t)blk * H_ * H_) : mUw;
  bf16* dst = WT + (size_t)blk * H_ * H_;
  for (int q = threadIdx.x; q < H_ * H_; q += 256) {
    int out = q >> 7, in = q & 127;
    dst[q] = __float2bfloat16(src[in * H_ + out]);
  }
}

// ---------------- per-layer small: node linears ----------------

__global__ __launch_bounds__(128) void k_node_lin(
    const float* __restrict__ x, const float* __restrict__ eVw,
    const float* __restrict__ eVb, const float* __restrict__ nUw,
    const float* __restrict__ nUb, const float* __restrict__ nVw,
    const float* __restrict__ nVb, const float* __restrict__ mask,
    float* __restrict__ Vxe, float* __restrict__ Ux, float* __restrict__ Vx) {
  __shared__ float xr[H_];
  int bi = blockIdx.x, h = threadIdx.x;
  xr[h] = x[(size_t)bi * H_ + h];
  __syncthreads();
  float m = mask[bi];
  float a = 0.f, bvv = 0.f, c = 0.f;
#pragma unroll 4
  for (int k = 0; k < H_; ++k) {
    float xv = xr[k];
    a   = fmaf(xv, eVw[k * H_ + h], a);
    bvv = fmaf(xv, nUw[k * H_ + h], bvv);
    c   = fmaf(xv, nVw[k * H_ + h], c);
  }
  Vxe[(size_t)bi * H_ + h] = m * (a + eVb[h]);
  Ux[(size_t)bi * H_ + h]  = m * (bvv + nUb[h]);
  Vx[(size_t)bi * H_ + h]  = m * (c + nVb[h]);
}

// ---------------- fused-staging helpers ----------------
// Produces v = this layer's A-row chunk (f32x4) for (row, k0); also updates
// e in place (MODE1) or materializes e0 (MODE0).

// pack f32x4 -> 8 bytes bf16, swizzled LDS write
#define LDS_PUT(SA, ROW, K0, V)                                            \
  {                                                                        \
    unsigned int p0 = ((unsigned int)f2b((V).y) << 16) | f2b((V).x);       \
    unsigned int p1 = ((unsigned int)f2b((V).w) << 16) | f2b((V).z);       \
    unsigned long long pk = ((unsigned long long)p1 << 32) | p0;           \
    int byo = ((ROW) << 8) + ((((K0) * 2)) ^ (((ROW) & 7) << 4));          \
    *(unsigned long long*)((SA) + byo) = pk;                               \
  }

// ---------------- big kernel: staged-update + GEMM + epilogue ------------
// MODE 0: first layer. A-row computed from raw inputs; e written (=e0).
// MODE 1: mid layer. A-row = e + relu(bn(etmp)) via ssPrev; e updated
//         in place; etmp (prev) read here, overwritten in compute phase.

template <int MODE>
__global__ __launch_bounds__(256, 3) void k_edge(
    float* __restrict__ e, bf16* __restrict__ etmp,
    const float* __restrict__ ssPrev, const int* __restrict__ xe,
    const float* __restrict__ ev, const float* __restrict__ w_eval,
    const float* __restrict__ emb, const bf16* __restrict__ WT,
    const float* __restrict__ eUb, const float* __restrict__ Vxe,
    const float* __restrict__ Vx, const float* __restrict__ Ux,
    const float* __restrict__ mask, float* __restrict__ xtmp,
    float* __restrict__ sums) {
  __shared__ __align__(16) char sA[MROWS_ * 256];
  const int bi = blockIdx.x;
  const int b = bi / N_;
  const int t = threadIdx.x;
  const int lane = t & 63;
  const int w = t >> 6;
  const float mask_i = mask[bi];

  // --- B fragments in registers (L2-hot WT) ---
  const int n0 = w << 5;
  const int colA = n0 + (lane & 15);
  const int colB = colA + 16;
  const int kgrp = (lane >> 4) << 3;  // element offset 0,8,16,24
  short8_t bfA[4], bfB[4];
  {
    const short* w0 = (const short*)WT + colA * H_ + kgrp;
    const short* w1 = (const short*)WT + colB * H_ + kgrp;
#pragma unroll
    for (int kk = 0; kk < 4; ++kk) {
      bfA[kk] = *(const short8_t*)(w0 + kk * 32);
      bfB[kk] = *(const short8_t*)(w1 + kk * 32);
    }
  }

  // --- staging: build A tile (bf16, swizzled) + fused e update ---
  {
    float* eb = e + (size_t)bi * N_ * H_;
    const unsigned short* tb =
        (const unsigned short*)etmp + (size_t)bi * N_ * H_;
    for (int q4 = t; q4 < MROWS_ * 32; q4 += 256) {
      int row = q4 >> 5, k0 = (q4 & 31) << 2;
      float4 v = make_float4(0.f, 0.f, 0.f, 0.f);
      if (row < N_) {
        if (MODE == 0) {
          if (k0 < 64) {
            float evv = ev[bi * N_ + row];
            v.x = evv * w_eval[k0 + 0];
            v.y = evv * w_eval[k0 + 1];
            v.z = evv * w_eval[k0 + 2];
            v.w = evv * w_eval[k0 + 3];
          } else {
            v = *(const float4*)(emb + xe[bi * N_ + row] * 64 + (k0 - 64));
          }
        } else {
          v = *(const float4*)(eb + row * H_ + k0);
          ushort4 tv = *(const ushort4*)(tb + row * H_ + k0);
          float mj = mask[b * N_ + row];
          bool msk = (mask_i * mj) > 0.f;
          float4 sc = *(const float4*)(ssPrev + k0);
          float4 sh = *(const float4*)(ssPrev + H_ + k0);
          float f0 = b2f16(tv.x), f1 = b2f16(tv.y);
          float f2 = b2f16(tv.z), f3 = b2f16(tv.w);
          v.x += fmaxf(msk ? fmaf(f0, sc.x, sh.x) : f0, 0.f);
          v.y += fmaxf(msk ? fmaf(f1, sc.y, sh.y) : f1, 0.f);
          v.z += fmaxf(msk ? fmaf(f2, sc.z, sh.z) : f2, 0.f);
          v.w += fmaxf(msk ? fmaf(f3, sc.w, sh.w) : f3, 0.f);
        }
        *(float4*)(eb + row * H_ + k0) = v;  // persist e_l
      }
      LDS_PUT(sA, row, k0, v)
    }
  }
  __syncthreads();

  // --- GEMM + gate/agg/BN-partials epilogue ---
  const float add0 = eUb[colA] + Vxe[(size_t)bi * H_ + colA];
  const float add1 = eUb[colB] + Vxe[(size_t)bi * H_ + colB];
  const float* VxeB = Vxe + (size_t)b * N_ * H_;
  const float* VxB  = Vx  + (size_t)b * N_ * H_;

  float agg0 = 0.f, agg1 = 0.f, den0 = 0.f, den1 = 0.f;
  float s1a = 0.f, s1b = 0.f, s2a = 0.f, s2b = 0.f;
  const int kb = (lane >> 4) << 4;  // byte offset of this lane's k-group

  for (int mt = 0; mt < MT_; ++mt) {
    f32x4 acc0 = {0.f, 0.f, 0.f, 0.f}, acc1 = {0.f, 0.f, 0.f, 0.f};
    int ra = mt * 16 + (lane & 15);
#pragma unroll
    for (int kk = 0; kk < 4; ++kk) {
      int ko = kk * 64 + kb;
      short8_t av = *(const short8_t*)(sA + (ra << 8) + (ko ^ ((ra & 7) << 4)));
      acc0 = __builtin_amdgcn_mfma_f32_16x16x32_bf16(av, bfA[kk], acc0, 0, 0, 0);
      acc1 = __builtin_amdgcn_mfma_f32_16x16x32_bf16(av, bfB[kk], acc1, 0, 0, 0);
    }
#pragma unroll
    for (int r = 0; r < 4; ++r) {
      int j = mt * 16 + ((lane >> 4) << 2) + r;
      bool valid = (j < N_);
      float mj = valid ? mask[b * N_ + j] : 0.f;
      float sqm = mask_i * mj;
      float vj0 = valid ? VxeB[(size_t)j * H_ + colA] : 0.f;
      float vj1 = valid ? VxeB[(size_t)j * H_ + colB] : 0.f;
      float t0 = acc0[r] + add0 + vj0;
      float t1 = acc1[r] + add1 + vj1;
      if (valid) {
        size_t o = ((size_t)bi * N_ + j) * H_;
        etmp[o + colA] = __float2bfloat16(t0);
        etmp[o + colB] = __float2bfloat16(t1);
      }
      float g0 = sqm / (1.f + __expf(-t0));
      float g1 = sqm / (1.f + __expf(-t1));
      float vx0 = valid ? VxB[(size_t)j * H_ + colA] : 0.f;
      float vx1 = valid ? VxB[(size_t)j * H_ + colB] : 0.f;
      agg0 = fmaf(g0, vx0, agg0);
      agg1 = fmaf(g1, vx1, agg1);
      den0 += g0; den1 += g1;
      s1a = fmaf(t0, sqm, s1a);
      s1b = fmaf(t1, sqm, s1b);
      s2a = fmaf(t0 * sqm, t0, s2a);
      s2b = fmaf(t1 * sqm, t1, s2b);
    }
  }
#pragma unroll
  for (int d = 16; d <= 32; d <<= 1) {
    agg0 += __shfl_xor(agg0, d); agg1 += __shfl_xor(agg1, d);
    den0 += __shfl_xor(den0, d); den1 += __shfl_xor(den1, d);
    s1a += __shfl_xor(s1a, d);   s1b += __shfl_xor(s1b, d);
    s2a += __shfl_xor(s2a, d);   s2b += __shfl_xor(s2b, d);
  }
  if ((lane >> 4) == 0) {
    atomicAdd(&sums[colA], s1a);
    atomicAdd(&sums[colB], s1b);
    atomicAdd(&sums[H_ + colA], s2a);
    atomicAdd(&sums[H_ + colB], s2b);
    float xt0 = Ux[(size_t)bi * H_ + colA] + agg0 / (1e-20f + den0);
    float xt1 = Ux[(size_t)bi * H_ + colB] + agg1 / (1e-20f + den1);
    xtmp[(size_t)bi * H_ + colA] = xt0;
    xtmp[(size_t)bi * H_ + colB] = xt1;
    atomicAdd(&sums[2 * H_ + colA], xt0 * mask_i);
    atomicAdd(&sums[3 * H_ + colA], xt0 * xt0 * mask_i);
    atomicAdd(&sums[2 * H_ + colB], xt1 * mask_i);
    atomicAdd(&sums[3 * H_ + colB], xt1 * xt1 * mask_i);
  }
}

// ---------------- BN finalize + x update ----------------

__global__ __launch_bounds__(128) void k_stats(
    const float* __restrict__ sums, const float* __restrict__ cnts,
    const float* __restrict__ gE, const float* __restrict__ bE,
    const float* __restrict__ gN, const float* __restrict__ bN,
    float* __restrict__ ss) {
  int h = threadIdx.x;
  float cntN = cnts[0], cntE = cnts[1];
  float mE = sums[h] / cntE;
  float vE = sums[H_ + h] / cntE - mE * mE;
  float scE = gE[h] * rsqrtf(vE + 1e-5f);
  ss[h] = scE;
  ss[H_ + h] = bE[h] - mE * scE;
  float mN = sums[2 * H_ + h] / cntN;
  float vN = sums[3 * H_ + h] / cntN - mN * mN;
  float scN = gN[h] * rsqrtf(vN + 1e-5f);
  ss[2 * H_ + h] = scN;
  ss[3 * H_ + h] = bN[h] - mN * scN;
}

__global__ __launch_bounds__(128) void k_xupd(const float* __restrict__ xtmp,
                                              const float* __restrict__ mask,
                                              const float* __restrict__ ss,
                                              float* __restrict__ x) {
  int bi = blockIdx.x, h = threadIdx.x;
  float mi = mask[bi];
  float tv = xtmp[(size_t)bi * H_ + h];
  float xn = (mi > 0.f) ? fmaf(tv, ss[2 * H_ + h], ss[3 * H_ + h]) : tv;
  x[(size_t)bi * H_ + h] += fmaxf(xn, 0.f);
}

// ---------------- head: A = e + relu(bn(etmp)); y = relu(A@U+bU)@V + bV ---

__global__ __launch_bounds__(256, 2) void k_head(
    const float* __restrict__ e, const bf16* __restrict__ etmp,
    const float* __restrict__ ssPrev, const bf16* __restrict__ UT,
    const float* __restrict__ Ub, const float* __restrict__ Vw,
    const float* __restrict__ Vb, const float* __restrict__ mask,
    float* __restrict__ y) {
  __shared__ __align__(16) char sA[MROWS_ * 256];
  __shared__ float part[4][MROWS_][2];
  const int bi = blockIdx.x;
  const int b = bi / N_;
  const int t = threadIdx.x;
  const int lane = t & 63;
  const int w = t >> 6;
  const float mask_i = mask[bi];

  const int n0 = w << 5;
  const int colA = n0 + (lane & 15);
  const int colB = colA + 16;
  const int kgrp = (lane >> 4) << 3;
  short8_t bfA[4], bfB[4];
  {
    const short* w0 = (const short*)UT + colA * H_ + kgrp;
    const short* w1 = (const short*)UT + colB * H_ + kgrp;
#pragma unroll
    for (int kk = 0; kk < 4; ++kk) {
      bfA[kk] = *(const short8_t*)(w0 + kk * 32);
      bfB[kk] = *(const short8_t*)(w1 + kk * 32);
    }
  }

  {
    const float* eb = e + (size_t)bi * N_ * H_;
    const unsigned short* tb =
        (const unsigned short*)etmp + (size_t)bi * N_ * H_;
    for (int q4 = t; q4 < MROWS_ * 32; q4 += 256) {
      int row = q4 >> 5, k0 = (q4 & 31) << 2;
      float4 v = make_float4(0.f, 0.f, 0.f, 0.f);
      if (row < N_) {
        v = *(const float4*)(eb + row * H_ + k0);
        ushort4 tv = *(const ushort4*)(tb + row * H_ + k0);
        float mj = mask[b * N_ + row];
        bool msk = (mask_i * mj) > 0.f;
        float4 sc = *(const float4*)(ssPrev + k0);
        float4 sh = *(const float4*)(ssPrev + H_ + k0);
        float f0 = b2f16(tv.x), f1 = b2f16(tv.y);
        float f2 = b2f16(tv.z), f3 = b2f16(tv.w);
        v.x += fmaxf(msk ? fmaf(f0, sc.x, sh.x) : f0, 0.f);
        v.y += fmaxf(msk ? fmaf(f1, sc.y, sh.y) : f1, 0.f);
        v.z += fmaxf(msk ? fmaf(f2, sc.z, sh.z) : f2, 0.f);
        v.w += fmaxf(msk ? fmaf(f3, sc.w, sh.w) : f3, 0.f);
      }
      LDS_PUT(sA, row, k0, v)
    }
  }
  __syncthreads();

  float bu0 = Ub[colA], bu1 = Ub[colB];
  float v00 = Vw[colA * 2], v01 = Vw[colA * 2 + 1];
  float v10 = Vw[colB * 2], v11 = Vw[colB * 2 + 1];
  const int kb = (lane >> 4) << 4;

  for (int mt = 0; mt < MT_; ++mt) {
    f32x4 acc0 = {0.f, 0.f, 0.f, 0.f}, acc1 = {0.f, 0.f, 0.f, 0.f};
    int ra = mt * 16 + (lane & 15);
#pragma unroll
    for (int kk = 0; kk < 4; ++kk) {
      int ko = kk * 64 + kb;
      short8_t av = *(const short8_t*)(sA + (ra << 8) + (ko ^ ((ra & 7) << 4)));
      acc0 = __builtin_amdgcn_mfma_f32_16x16x32_bf16(av, bfA[kk], acc0, 0, 0, 0);
      acc1 = __builtin_amdgcn_mfma_f32_16x16x32_bf16(av, bfB[kk], acc1, 0, 0, 0);
    }
#pragma unroll
    for (int r = 0; r < 4; ++r) {
      float h0v = fmaxf(acc0[r] + bu0, 0.f);
      float h1v = fmaxf(acc1[r] + bu1, 0.f);
      float p0 = h0v * v00 + h1v * v10;
      float p1 = h0v * v01 + h1v * v11;
#pragma unroll
      for (int d = 1; d < 16; d <<= 1) {
        p0 += __shfl_xor(p0, d);
        p1 += __shfl_xor(p1, d);
      }
      int j = mt * 16 + ((lane >> 4) << 2) + r;
      if ((lane & 15) == 0) { part[w][j][0] = p0; part[w][j][1] = p1; }
    }
  }
  __syncthreads();
  float vb0 = Vb[0], vb1 = Vb[1];
  for (int q = t; q < N_ * 2; q += 256) {
    int j = q >> 1, c = q & 1;
    float s = part[0][j][c] + part[1][j][c] + part[2][j][c] + part[3][j][c] +
              (c ? vb1 : vb0);
    y[((size_t)bi * N_ + j) * 2 + c] = s;
  }
}

// ---------------- launch ----------------

extern "C" void kernel_launch(void* const* d_in, const int* in_sizes, int n_in,
                              void* d_out, int out_size, void* d_ws,
                              size_t ws_size, hipStream_t stream) {
  const int*   x_edges = (const int*)d_in[0];
  const float* ev      = (const float*)d_in[1];
  const float* coord   = (const float*)d_in[2];
  const float* mask    = (const float*)d_in[3];
  const float* w_coord = (const float*)d_in[4];
  const float* w_eval  = (const float*)d_in[5];
  const float* emb     = (const float*)d_in[6];
  const float* eUw = (const float*)d_in[7];
  const float* eUb = (const float*)d_in[8];
  const float* eVw = (const float*)d_in[9];
  const float* eVb = (const float*)d_in[10];
  const float* nUw = (const float*)d_in[11];
  const float* nUb = (const float*)d_in[12];
  const float* nVw = (const float*)d_in[13];
  const float* nVb = (const float*)d_in[14];
  const float* gE  = (const float*)d_in[15];
  const float* bE  = (const float*)d_in[16];
  const float* gN  = (const float*)d_in[17];
  const float* bN  = (const float*)d_in[18];
  const float* mUw = (const float*)d_in[19];
  const float* mUb = (const float*)d_in[20];
  const float* mVw = (const float*)d_in[21];
  const float* mVb = (const float*)d_in[22];

  char* ws = (char*)d_ws;
  size_t off = 0;
  auto alloc = [&](size_t bytes) {
    void* p = ws + off;
    off += (bytes + 255) & ~(size_t)255;
    return p;
  };
  float* e    = (float*)alloc((size_t)B_ * N_ * N_ * H_ * 4);  // 81.92 MB
  bf16* etmp  = (bf16*)alloc((size_t)B_ * N_ * N_ * H_ * 2);   // 40.96 MB
  float* x    = (float*)alloc((size_t)BN_ * H_ * 4);
  float* Vxe  = (float*)alloc((size_t)BN_ * H_ * 4);
  float* Ux   = (float*)alloc((size_t)BN_ * H_ * 4);
  float* Vx   = (float*)alloc((size_t)BN_ * H_ * 4);
  float* xtmp = (float*)alloc((size_t)BN_ * H_ * 4);
  float* sums = (float*)alloc(4 * H_ * 4);
  float* ss   = (float*)alloc(4 * H_ * 4);
  float* cnts = (float*)alloc(256);
  bf16* WT    = (bf16*)alloc((size_t)4 * H_ * H_ * 2);

  k_prep_w<<<4, 256, 0, stream>>>(eUw, mUw, WT);
  k_init_x<<<BN_, 128, 0, stream>>>(coord, w_coord, x);
  k_cnt<<<1, 256, 0, stream>>>(mask, cnts);

  for (int l = 0; l < 3; ++l) {
    size_t wo = (size_t)l * H_ * H_;
    size_t bo = (size_t)l * H_;
    hipMemsetAsync(sums, 0, 4 * H_ * 4, stream);
    k_node_lin<<<BN_, 128, 0, stream>>>(x, eVw + wo, eVb + bo, nUw + wo,
                                        nUb + bo, nVw + wo, nVb + bo, mask,
                                        Vxe, Ux, Vx);
    if (l == 0) {
      k_edge<0><<<BN_, 256, 0, stream>>>(e, etmp, ss, x_edges, ev, w_eval,
                                         emb, WT + wo, eUb + bo, Vxe, Vx, Ux,
                                         mask, xtmp, sums);
    } else {
      k_edge<1><<<BN_, 256, 0, stream>>>(e, etmp, ss, x_edges, ev, w_eval,
                                         emb, WT + wo, eUb + bo, Vxe, Vx, Ux,
                                         mask, xtmp, sums);
    }
    k_stats<<<1, 128, 0, stream>>>(sums, cnts, gE + bo, bE + bo, gN + bo,
                                   bN + bo, ss);
    if (l < 2) k_xupd<<<BN_, 128, 0, stream>>>(xtmp, mask, ss, x);
  }
  k_head<<<BN_, 256, 0, stream>>>(e, etmp, ss, WT + (size_t)3 * H_ * H_, mUb,
                                  mVw, mVb, mask, (float*)d_out);
}